// Round 2
// baseline (252.029 us; speedup 1.0000x reference)
//
#include <hip/hip_runtime.h>
#include <math.h>
#include <stdint.h>

// Problem dims (fixed by setup_inputs)
#define B_N 256
#define C_N 1152
#define I_N 8
#define N_N 10
#define D_N 16

constexpr int C_PER    = 18;             // c's per route block
constexpr int C_CHUNKS = C_N / C_PER;    // 64
constexpr int STAGE_C  = 3;              // c's per W staging round (double-buffered)
constexpr int N_STAGES = 6;
constexpr int BLOCK    = 256;
// route grid = 64 x 16 = 1024 blocks = exactly 4 blocks/CU -> full co-residency
// (required for the software grid barrier; __launch_bounds__(256,4) + 31.7KB LDS
//  guarantee 4 blocks/CU)

typedef short v8s __attribute__((ext_vector_type(8)));
typedef float v4f __attribute__((ext_vector_type(4)));

// ---- LDS pool (bytes), fused kernel ----
//   wbuf (short): 2 x [3c][10n][16d][8i] = 15360 @ 0      (DMA, linear, dbuf)
//   xs   (short): [18c][16b][8i]         =  4608 @ 15360  (DMA once, persists)
//   vst  (float): [16b][164]             = 10496 @ 19968  (DMA, linear, padded)
//   cfl  (float): [3c][163]              =  1956 @ 30464
//   comb (float): [16b][164] ALIASES wbuf                 @ 0
constexpr int POOL_BYTES = 32432;   // 31.7 KB -> 4 blocks/CU

// ws layout (floats unless noted):
constexpr size_t VSTG_FL = 16 * 16 * 164;
constexpr size_t PS_FL   = (size_t)C_CHUNKS * B_N * 160;
constexpr size_t WB_SH   = (size_t)C_N * 1280;
constexpr size_t XT_SH   = (size_t)1024 * 2304;
constexpr int    BAR_W   = 576;     // 18 cachelines x 32 uints

#define GLD16(g, l)                                                         \
    __builtin_amdgcn_global_load_lds(                                       \
        (const uint32_t __attribute__((address_space(1)))*)(g),             \
        (uint32_t __attribute__((address_space(3)))*)(l), 16, 0, 0)

// RNE pack of 2 f32 -> 1 u32 of 2 bf16 (bitwise identical to manual RNE)
__device__ __forceinline__ uint32_t cvtpk(float a, float b) {
    uint32_t r;
    asm("v_cvt_pk_bf16_f32 %0, %1, %2" : "=v"(r) : "v"(a), "v"(b));
    return r;
}
__device__ __forceinline__ float bf2f(short s) {
    return __uint_as_float(((uint32_t)(uint16_t)s) << 16);
}

// ---- K0: fused W and x conversion + barrier-state init (one dispatch) ----
__global__ __launch_bounds__(BLOCK)
void conv_all(const float* __restrict__ x, const float* __restrict__ W,
              short* __restrict__ Wb, short* __restrict__ xt,
              uint32_t* __restrict__ bar)
{
    if (blockIdx.x < 144) {
        // barrier counters zeroed here, a dispatch BEFORE any use -> race-free
        if (blockIdx.x == 0) {
            for (int i = threadIdx.x; i < BAR_W; i += BLOCK) bar[i] = 0u;
        }
        const int c0 = blockIdx.x * 8;
        const int cc = threadIdx.x >> 5;        // 8 c's per block
        const int k4 = threadIdx.x & 31;        // 32 float4 per (n,c)
        const float4* W4 = (const float4*)W;
        uint2* dst = (uint2*)Wb;
        for (int n = 0; n < N_N; ++n) {
            float4 v = W4[(size_t)n * 36864 + (size_t)(c0 + cc) * 32 + k4];
            dst[(((size_t)(c0 + cc) * 1280 + n * 128) >> 2) + k4] =
                make_uint2(cvtpk(v.x, v.y), cvtpk(v.z, v.w));
        }
    } else {
        const int tile  = blockIdx.x - 144;      // chunk*16 + btile
        const int chunk = tile >> 4;
        const int btile = tile & 15;
        const int c0    = chunk * C_PER;
        const int gb0   = btile * 16;
        const float4* x4 = (const float4*)x;
        uint2* dst = (uint2*)(xt + (size_t)tile * 2304);
        #pragma unroll
        for (int it = 0; it < 3; ++it) {
            int f = threadIdx.x + BLOCK * it;    // < 576 float4
            if (f < 576) {
                int b = f / 36, r = f - b * 36;  // r: 36 float4 per b (18c*8i)
                float4 v = x4[(size_t)(gb0 + b) * 2304 + c0 * 2 + r];
                int cp = r >> 1, i0 = (r & 1) * 4;
                dst[((cp * 128 + b * 8 + i0) >> 2)] =
                    make_uint2(cvtpk(v.x, v.y), cvtpk(v.z, v.w));
            }
        }
    }
}

// ---- software grid barrier (1024 co-resident blocks) ----
// Entry: every wave drains its own vmem, block-syncs; leader release-fences
// (s_waitcnt + buffer_wbl2 sc1 -> cross-XCD visibility of this block's stores),
// two-level arrival (16 sub-counters x 64 -> top x 16 -> monotonic phase).
// Spin: relaxed agent loads (LLC, no L2 invalidate per poll) + s_sleep;
// one acquire fence (buffer_inv sc1) on exit.
__device__ __forceinline__ void gbar(uint32_t* bar, int bid, uint32_t expect)
{
    asm volatile("s_waitcnt vmcnt(0) lgkmcnt(0)" ::: "memory");
    __syncthreads();
    if (threadIdx.x == 0) {
        __builtin_amdgcn_fence(__ATOMIC_RELEASE, "agent");
        uint32_t a = __hip_atomic_fetch_add(&bar[(bid & 15) * 32], 1u,
                                            __ATOMIC_RELAXED,
                                            __HIP_MEMORY_SCOPE_AGENT);
        if (a == 63u) {
            uint32_t t = __hip_atomic_fetch_add(&bar[16 * 32], 1u,
                                                __ATOMIC_RELAXED,
                                                __HIP_MEMORY_SCOPE_AGENT);
            if (t == 15u) {
                // last block: reset counters, then publish phase (release
                // orders the resets before the phase bump)
                #pragma unroll
                for (int i = 0; i < 17; ++i)
                    __hip_atomic_store(&bar[i * 32], 0u, __ATOMIC_RELAXED,
                                       __HIP_MEMORY_SCOPE_AGENT);
                __hip_atomic_fetch_add(&bar[17 * 32], 1u, __ATOMIC_RELEASE,
                                       __HIP_MEMORY_SCOPE_AGENT);
            }
        }
        while (__hip_atomic_load(&bar[17 * 32], __ATOMIC_RELAXED,
                                 __HIP_MEMORY_SCOPE_AGENT) < expect)
            __builtin_amdgcn_s_sleep(2);
        __builtin_amdgcn_fence(__ATOMIC_ACQUIRE, "agent");
    }
    __syncthreads();
}

// ---- one routing pass (validated R1 structure, function-ized) ----
template <bool FIRST>
__device__ __forceinline__ void route_core(
    short* wbuf, const short* xs, float* vst, float* cfl, float* comb,
    const short* __restrict__ Wb, const float* __restrict__ vstG,
    float* __restrict__ p_s, int chunk, int btile)
{
    const int tid  = threadIdx.x;
    const int wv   = tid >> 6;
    const int lane = tid & 63;
    const int b    = lane & 15;   // D-col / B-col; also A-row m (=d)
    const int quad = lane >> 4;
    const int gb0  = btile * 16;
    const int c0   = chunk * C_PER;

    // ---- prologue DMA: vst (656x16B, !FIRST), W0, W1 (480x16B each) ----
    if (!FIRST) {
        const char* src = (const char*)(vstG + (size_t)btile * 2624);
        #pragma unroll
        for (int it = 0; it < 3; ++it) {
            int f = tid + BLOCK * it;
            if (f < 656) GLD16(src + f * 16, (char*)vst + f * 16);
        }
        asm volatile("" ::: "memory");
    }
    #pragma unroll
    for (int s0 = 0; s0 < 2; ++s0) {
        const char* src = (const char*)(Wb + (size_t)(c0 + s0 * STAGE_C) * 1280);
        char* dst = (char*)(wbuf + s0 * (STAGE_C * 1280));
        #pragma unroll
        for (int it = 0; it < 2; ++it) {
            int f = tid + BLOCK * it;
            if (f < 480) GLD16(src + f * 16, dst + f * 16);
        }
        asm volatile("" ::: "memory");
    }
    // W stages are uniformly 2 GLD16/wave; vmcnt(2) -> everything but W1 landed
    asm volatile("s_waitcnt vmcnt(2)" ::: "memory");
    __builtin_amdgcn_s_barrier();

    const int ncnt = (wv < 2) ? 3 : 2;   // wave wv owns n = wv, wv+4, (wv+8)
    v4f sacc[3];
    sacc[0] = (v4f){0.f, 0.f, 0.f, 0.f};
    sacc[1] = (v4f){0.f, 0.f, 0.f, 0.f};
    sacc[2] = (v4f){0.f, 0.f, 0.f, 0.f};

    for (int st = 0; st < N_STAGES; ++st) {
        const short* Ws = wbuf + (st & 1) * (STAGE_C * 1280);

        // issue W[st+1] DMA into the buffer last read at stage st-1
        if (st >= 1 && st < N_STAGES - 1) {
            const char* src =
                (const char*)(Wb + (size_t)(c0 + (st + 1) * STAGE_C) * 1280);
            char* dst = (char*)(wbuf + ((st + 1) & 1) * (STAGE_C * 1280));
            #pragma unroll
            for (int it = 0; it < 2; ++it) {
                int f = tid + BLOCK * it;
                if (f < 480) GLD16(src + f * 16, dst + f * 16);
            }
            asm volatile("" ::: "memory");
        }

        if (!FIRST) {
            // ---- sweep1: 30 independent (c,n) chains over 4 waves ----
            #pragma unroll
            for (int k = 0; k < 8; ++k) {
                const int idx = wv + 4 * k;
                if (idx < 30) {
                    const int c = idx / 10;
                    const int n = idx - c * 10;
                    v8s wa = {0, 0, 0, 0, 0, 0, 0, 0};
                    if (quad == 0)
                        wa = *(const v8s*)(Ws + c * 1280 + n * 128 + b * 8);
                    const v8s xb =
                        *(const v8s*)(xs + (st * STAGE_C + c) * 128 + b * 8);
                    v4f u = __builtin_amdgcn_mfma_f32_16x16x32_bf16(
                        wa, xb, (v4f){0.f, 0.f, 0.f, 0.f}, 0, 0, 0);
                    const float4 v4 =
                        *(const float4*)(vst + b * 164 + n * 16 + quad * 4);
                    float l = u[0] * v4.x + u[1] * v4.y + u[2] * v4.z + u[3] * v4.w;
                    l += __shfl_xor(l, 16);
                    l += __shfl_xor(l, 32);
                    const float e1 = __expf(l);   // |l| <~ 3: no max-sub needed
                    if (quad == 0) cfl[c * 163 + n * 16 + b] = e1;
                }
            }
            // publish cfl; W[st+1] DMA stays in flight (no vmcnt drain)
            asm volatile("s_waitcnt lgkmcnt(0)" ::: "memory");
            __builtin_amdgcn_s_barrier();
        }

        // ---- sweep2: K=32 packs 3 c's (quad=c, quad3 zero-padded) ----
        {
            const bool valid = (quad < STAGE_C);
            const int  cl    = valid ? quad : 0;
            const v8s xq =
                *(const v8s*)(xs + (st * STAGE_C + cl) * 128 + b * 8);
            float xf[8];
            #pragma unroll
            for (int j = 0; j < 8; ++j) xf[j] = bf2f(xq[j]);

            if (FIRST) {
                union { v8s s; uint32_t u[4]; } zu;
                zu.u[0] = cvtpk(0.1f * xf[0], 0.1f * xf[1]);
                zu.u[1] = cvtpk(0.1f * xf[2], 0.1f * xf[3]);
                zu.u[2] = cvtpk(0.1f * xf[4], 0.1f * xf[5]);
                zu.u[3] = cvtpk(0.1f * xf[6], 0.1f * xf[7]);
                #pragma unroll
                for (int jj = 0; jj < 3; ++jj) {
                    if (jj < ncnt) {
                        const int n = wv + 4 * jj;
                        v8s wa = {0, 0, 0, 0, 0, 0, 0, 0};
                        if (valid)
                            wa = *(const v8s*)(Ws + cl * 1280 + n * 128 + b * 8);
                        sacc[jj] = __builtin_amdgcn_mfma_f32_16x16x32_bf16(
                            wa, zu.s, sacc[jj], 0, 0, 0);
                    }
                }
            } else {
                float Z = 0.f;
                #pragma unroll
                for (int n = 0; n < N_N; ++n) Z += cfl[cl * 163 + n * 16 + b];
                const float rzv = __builtin_amdgcn_rcpf(Z);
                #pragma unroll
                for (int jj = 0; jj < 3; ++jj) {
                    if (jj < ncnt) {
                        const int n = wv + 4 * jj;
                        const float cv = cfl[cl * 163 + n * 16 + b] * rzv;
                        union { v8s s; uint32_t u[4]; } zu;
                        zu.u[0] = cvtpk(cv * xf[0], cv * xf[1]);
                        zu.u[1] = cvtpk(cv * xf[2], cv * xf[3]);
                        zu.u[2] = cvtpk(cv * xf[4], cv * xf[5]);
                        zu.u[3] = cvtpk(cv * xf[6], cv * xf[7]);
                        v8s wa = {0, 0, 0, 0, 0, 0, 0, 0};
                        if (valid)
                            wa = *(const v8s*)(Ws + cl * 1280 + n * 128 + b * 8);
                        sacc[jj] = __builtin_amdgcn_mfma_f32_16x16x32_bf16(
                            wa, zu.s, sacc[jj], 0, 0, 0);
                    }
                }
            }
        }

        // end of stage: W[st+1] had a full stage of compute to land
        asm volatile("s_waitcnt vmcnt(0) lgkmcnt(0)" ::: "memory");
        __builtin_amdgcn_s_barrier();
    }

    // loop-end barrier already synced all Ws/xs/cfl readers -> comb alias safe
    #pragma unroll
    for (int jj = 0; jj < 3; ++jj) {
        if (jj < ncnt) {
            const int n = wv + 4 * jj;
            #pragma unroll
            for (int r = 0; r < 4; ++r)
                comb[b * 164 + n * 16 + quad * 4 + r] = sacc[jj][r];
        }
    }
    __syncthreads();
    #pragma unroll
    for (int it = 0; it < 3; ++it) {
        int f = tid + BLOCK * it;
        if (f < 640) {
            int e = f * 4;
            int bb = e / 160, rem = e - bb * 160;
            float4 v = *(const float4*)(comb + bb * 164 + rem);
            *(float4*)(&p_s[((size_t)chunk * B_N + gb0 + bb) * 160 + rem]) = v;
        }
    }
}

// ---- reduce+squash phase (in-kernel): warp gw handles g = b*10+n ----
__device__ __forceinline__ void reduce_core(const float* __restrict__ p_s,
                                            float* __restrict__ vstG,
                                            float* __restrict__ out,
                                            int phase, int bid)
{
    const int wv   = threadIdx.x >> 6;
    const int lane = threadIdx.x & 63;
    const int g    = wv * 1024 + bid;        // covers 0..2559 with wv<3
    if (g >= B_N * N_N) return;              // wave-uniform, no barriers below
    const int q = lane & 3;
    const int h = lane >> 2;

    float4 s = make_float4(0.f, 0.f, 0.f, 0.f);
    #pragma unroll
    for (int m = 0; m < C_CHUNKS / 16; ++m) {   // 4
        const int cc = h + 16 * m;
        float4 v = *(const float4*)(&p_s[((size_t)cc * (B_N * N_N) + g) * D_N + q * 4]);
        s.x += v.x; s.y += v.y; s.z += v.z; s.w += v.w;
    }
    #pragma unroll
    for (int off = 4; off < 64; off <<= 1) {
        s.x += __shfl_xor(s.x, off);
        s.y += __shfl_xor(s.y, off);
        s.z += __shfl_xor(s.z, off);
        s.w += __shfl_xor(s.w, off);
    }
    float sq = s.x * s.x + s.y * s.y + s.z * s.z + s.w * s.w;
    sq += __shfl_xor(sq, 1);
    sq += __shfl_xor(sq, 2);

    const float scale = (sq / (1.f + sq)) / (sqrtf(sq) + 1e-8f);
    const float4 v = make_float4(scale * s.x, scale * s.y, scale * s.z, scale * s.w);

    if (h == 0) {
        if (phase == 2) {
            *(float4*)(&out[(size_t)g * D_N + q * 4]) = v;
        } else {
            const int bb = g / 10, n = g - bb * 10;
            float* vp = vstG + (size_t)(bb >> 4) * 2624 + (bb & 15) * 164 + n * 16 + q * 4;
            if (phase == 0) {
                *(float4*)vp = v;
            } else {
                float4 o = *(const float4*)vp;
                *(float4*)vp = make_float4(o.x + v.x, o.y + v.y, o.z + v.z, o.w + v.w);
            }
        }
    }
}

// ---- the whole routing pipeline in ONE dispatch (5 grid barriers) ----
__global__ __launch_bounds__(BLOCK, 4)
void fused_route(const short* __restrict__ Wb, const short* __restrict__ xt,
                 float* __restrict__ vstG, float* __restrict__ p_s,
                 float* __restrict__ out, uint32_t* bar)
{
    __shared__ __align__(16) char pool[POOL_BYTES];
    short* wbuf = (short*)pool;
    short* xs   = (short*)(pool + 15360);
    float* vst  = (float*)(pool + 19968);
    float* cfl  = (float*)(pool + 30464);
    float* comb = (float*)pool;

    const int chunk = blockIdx.x;
    const int btile = blockIdx.y;
    const int bid   = btile * 64 + chunk;   // 0..1023
    const int tid   = threadIdx.x;

    // ---- xs DMA once; persists in LDS across all 3 passes ----
    {
        const char* src = (const char*)(xt + (size_t)(chunk * 16 + btile) * 2304);
        #pragma unroll
        for (int it = 0; it < 2; ++it) {
            int f = tid + BLOCK * it;
            if (f < 288) GLD16(src + f * 16, (char*)xs + f * 16);
        }
        asm volatile("" ::: "memory");
    }

    route_core<true>(wbuf, xs, vst, cfl, comb, Wb, vstG, p_s, chunk, btile);
    gbar(bar, bid, 1);
    reduce_core(p_s, vstG, out, 0, bid);
    gbar(bar, bid, 2);

    #pragma unroll 1
    for (int pass = 1; pass <= 2; ++pass) {
        route_core<false>(wbuf, xs, vst, cfl, comb, Wb, vstG, p_s, chunk, btile);
        gbar(bar, bid, (uint32_t)(2 * pass + 1));
        reduce_core(p_s, vstG, out, pass == 2 ? 2 : 1, bid);
        if (pass == 1) gbar(bar, bid, 4);
    }
}

extern "C" void kernel_launch(void* const* d_in, const int* in_sizes, int n_in,
                              void* d_out, int out_size, void* d_ws, size_t ws_size,
                              hipStream_t stream)
{
    const float* x = (const float*)d_in[0];
    const float* W = (const float*)d_in[1];
    float* out  = (float*)d_out;

    float* vstG = (float*)d_ws;
    float* p_s  = vstG + VSTG_FL;
    short* Wb   = (short*)(p_s + PS_FL);
    short* xt   = Wb + WB_SH;
    uint32_t* bar = (uint32_t*)(xt + XT_SH);

    conv_all<<<dim3(144 + 1024), BLOCK, 0, stream>>>(x, W, Wb, xt, bar);
    fused_route<<<dim3(C_CHUNKS, 16), BLOCK, 0, stream>>>(Wb, xt, vstG, p_s, out, bar);
}

// Round 3
// 132.762 us; speedup vs baseline: 1.8984x; 1.8984x over previous
//
#include <hip/hip_runtime.h>
#include <math.h>
#include <stdint.h>

// Problem dims (fixed by setup_inputs)
#define B_N 256
#define C_N 1152
#define I_N 8
#define N_N 10
#define D_N 16

constexpr int C_PER    = 18;             // c's per route block
constexpr int C_CHUNKS = C_N / C_PER;    // 64
constexpr int STAGE_C  = 3;              // c's per W staging round (double-buffered)
constexpr int N_STAGES = 6;
constexpr int BLOCK    = 256;
// route grid = 64 x 16 = 1024 blocks = exactly 4 blocks/CU -> full co-residency

typedef short v8s __attribute__((ext_vector_type(8)));
typedef float v4f __attribute__((ext_vector_type(4)));

// ---- LDS pool (bytes), fused kernel ----
//   wbuf (short): 2 x [3c][10n][16d][8i] = 15360 @ 0      (DMA, linear, dbuf)
//   xs   (short): [18c][16b][8i]         =  4608 @ 15360  (DMA once, persists)
//   vst  (float): [16b][164]             = 10496 @ 19968  (sc1 reg-staged)
//   cfl  (float): [3c][163]              =  1956 @ 30464
//   comb (float): [16b][164] ALIASES wbuf                 @ 0
constexpr int POOL_BYTES = 32432;   // 31.7 KB -> 4 blocks/CU

// ws layout (floats unless noted):
constexpr size_t VSTG_FL = 16 * 16 * 164;
constexpr size_t PS_FL   = (size_t)C_CHUNKS * B_N * 160;
constexpr size_t WB_SH   = (size_t)C_N * 1280;
constexpr size_t XT_SH   = (size_t)1024 * 2304;
constexpr int    BAR_W   = 576;     // 18 cachelines x 32 uints

#define GLD16(g, l)                                                         \
    __builtin_amdgcn_global_load_lds(                                       \
        (const uint32_t __attribute__((address_space(1)))*)(g),             \
        (uint32_t __attribute__((address_space(3)))*)(l), 16, 0, 0)

// ---- agent-coherent (LLC, bypass per-XCD L2) 16B load/store: sc1 flag ----
// Per gfx94x/gfx95x memory model, agent scope == sc1; retire (vmcnt) of an
// sc1 store implies LLC visibility. Loads fold their waitcnt into the asm
// block (compiler can't track inline-asm vmcnt - rule #18 analog).
__device__ __forceinline__ void st16_sc1(float* p, v4f v) {
    asm volatile("global_store_dwordx4 %0, %1, off sc1"
                 :: "v"(p), "v"(v) : "memory");
}
__device__ __forceinline__ v4f ld16_sc1(const float* p) {
    v4f v;
    asm volatile("global_load_dwordx4 %0, %1, off sc1\n\t"
                 "s_waitcnt vmcnt(0)"
                 : "=&v"(v) : "v"(p) : "memory");
    return v;
}

// RNE pack of 2 f32 -> 1 u32 of 2 bf16 (bitwise identical to manual RNE)
__device__ __forceinline__ uint32_t cvtpk(float a, float b) {
    uint32_t r;
    asm("v_cvt_pk_bf16_f32 %0, %1, %2" : "=v"(r) : "v"(a), "v"(b));
    return r;
}
__device__ __forceinline__ float bf2f(short s) {
    return __uint_as_float(((uint32_t)(uint16_t)s) << 16);
}

// ---- K0: fused W and x conversion + barrier-state init (one dispatch) ----
__global__ __launch_bounds__(BLOCK)
void conv_all(const float* __restrict__ x, const float* __restrict__ W,
              short* __restrict__ Wb, short* __restrict__ xt,
              uint32_t* __restrict__ bar)
{
    if (blockIdx.x < 144) {
        // barrier counters zeroed here, a dispatch BEFORE any use -> race-free
        if (blockIdx.x == 0) {
            for (int i = threadIdx.x; i < BAR_W; i += BLOCK) bar[i] = 0u;
        }
        const int c0 = blockIdx.x * 8;
        const int cc = threadIdx.x >> 5;        // 8 c's per block
        const int k4 = threadIdx.x & 31;        // 32 float4 per (n,c)
        const float4* W4 = (const float4*)W;
        uint2* dst = (uint2*)Wb;
        for (int n = 0; n < N_N; ++n) {
            float4 v = W4[(size_t)n * 36864 + (size_t)(c0 + cc) * 32 + k4];
            dst[(((size_t)(c0 + cc) * 1280 + n * 128) >> 2) + k4] =
                make_uint2(cvtpk(v.x, v.y), cvtpk(v.z, v.w));
        }
    } else {
        const int tile  = blockIdx.x - 144;      // chunk*16 + btile
        const int chunk = tile >> 4;
        const int btile = tile & 15;
        const int c0    = chunk * C_PER;
        const int gb0   = btile * 16;
        const float4* x4 = (const float4*)x;
        uint2* dst = (uint2*)(xt + (size_t)tile * 2304);
        #pragma unroll
        for (int it = 0; it < 3; ++it) {
            int f = threadIdx.x + BLOCK * it;    // < 576 float4
            if (f < 576) {
                int b = f / 36, r = f - b * 36;  // r: 36 float4 per b (18c*8i)
                float4 v = x4[(size_t)(gb0 + b) * 2304 + c0 * 2 + r];
                int cp = r >> 1, i0 = (r & 1) * 4;
                dst[((cp * 128 + b * 8 + i0) >> 2)] =
                    make_uint2(cvtpk(v.x, v.y), cvtpk(v.z, v.w));
            }
        }
    }
}

// ---- fence-free software grid barrier (1024 co-resident blocks) ----
// All cross-block data moves via sc1 (LLC-coherent) ops, so NO cache
// maintenance (buffer_wbl2/buffer_inv) is needed here - that per-leader
// wbinv storm was R2's 170us. vmcnt(0) drain + two-level relaxed agent
// atomics + monotonic phase publish.
__device__ __forceinline__ void gbar(uint32_t* bar, int bid, uint32_t expect)
{
    asm volatile("s_waitcnt vmcnt(0) lgkmcnt(0)" ::: "memory");
    __syncthreads();
    if (threadIdx.x == 0) {
        uint32_t a = __hip_atomic_fetch_add(&bar[(bid & 15) * 32], 1u,
                                            __ATOMIC_RELAXED,
                                            __HIP_MEMORY_SCOPE_AGENT);
        if (a == 63u) {
            uint32_t t = __hip_atomic_fetch_add(&bar[16 * 32], 1u,
                                                __ATOMIC_RELAXED,
                                                __HIP_MEMORY_SCOPE_AGENT);
            if (t == 15u) {
                // last block: reset counters (sc1 stores), drain, bump phase
                #pragma unroll
                for (int i = 0; i < 17; ++i)
                    __hip_atomic_store(&bar[i * 32], 0u, __ATOMIC_RELAXED,
                                       __HIP_MEMORY_SCOPE_AGENT);
                asm volatile("s_waitcnt vmcnt(0)" ::: "memory");
                __hip_atomic_fetch_add(&bar[17 * 32], 1u, __ATOMIC_RELAXED,
                                       __HIP_MEMORY_SCOPE_AGENT);
            }
        }
        while (__hip_atomic_load(&bar[17 * 32], __ATOMIC_RELAXED,
                                 __HIP_MEMORY_SCOPE_AGENT) < expect)
            __builtin_amdgcn_s_sleep(2);
    }
    __syncthreads();
}

// ---- one routing pass ----
template <bool FIRST>
__device__ __forceinline__ void route_core(
    short* wbuf, const short* xs, float* vst, float* cfl, float* comb,
    const short* __restrict__ Wb, const float* __restrict__ vstG,
    float* __restrict__ p_s, int chunk, int btile)
{
    const int tid  = threadIdx.x;
    const int wv   = tid >> 6;
    const int lane = tid & 63;
    const int b    = lane & 15;   // D-col / B-col; also A-row m (=d)
    const int quad = lane >> 4;
    const int gb0  = btile * 16;
    const int c0   = chunk * C_PER;

    // ---- prologue: vst via sc1 reg-staging (cross-block data!), W0/W1 DMA ----
    if (!FIRST) {
        const float* src = vstG + (size_t)btile * 2624;
        const int f0 = tid;                       // < 656 always
        const int f1 = tid + 256;                 // < 656 always
        int f2 = tid + 512; f2 = (f2 < 656) ? f2 : 655;  // clamp: uniform count
        v4f t0, t1, t2;
        asm volatile(
            "global_load_dwordx4 %0, %3, off sc1\n\t"
            "global_load_dwordx4 %1, %4, off sc1\n\t"
            "global_load_dwordx4 %2, %5, off sc1\n\t"
            "s_waitcnt vmcnt(0)"
            : "=&v"(t0), "=&v"(t1), "=&v"(t2)
            : "v"(src + f0 * 4), "v"(src + f1 * 4), "v"(src + f2 * 4)
            : "memory");
        *(v4f*)((char*)vst + f0 * 16) = t0;
        *(v4f*)((char*)vst + f1 * 16) = t1;
        *(v4f*)((char*)vst + f2 * 16) = t2;   // f2 clamp: benign dup write
    }
    // W0 then W1 via cached global_load_lds (Wb immutable -> L2-warm reuse);
    // 480-split gives every wave exactly 2 GLD16 per stage (uniform vmcnt)
    #pragma unroll
    for (int s0 = 0; s0 < 2; ++s0) {
        const char* src = (const char*)(Wb + (size_t)(c0 + s0 * STAGE_C) * 1280);
        char* dst = (char*)(wbuf + s0 * (STAGE_C * 1280));
        #pragma unroll
        for (int it = 0; it < 2; ++it) {
            int f = tid + BLOCK * it;
            if (f < 480) GLD16(src + f * 16, dst + f * 16);
        }
        asm volatile("" ::: "memory");
    }
    // vmcnt(2): W0 (and everything earlier) landed; W1 still in flight
    asm volatile("s_waitcnt vmcnt(2) lgkmcnt(0)" ::: "memory");
    __builtin_amdgcn_s_barrier();

    const int ncnt = (wv < 2) ? 3 : 2;   // wave wv owns n = wv, wv+4, (wv+8)
    v4f sacc[3];
    sacc[0] = (v4f){0.f, 0.f, 0.f, 0.f};
    sacc[1] = (v4f){0.f, 0.f, 0.f, 0.f};
    sacc[2] = (v4f){0.f, 0.f, 0.f, 0.f};

    for (int st = 0; st < N_STAGES; ++st) {
        const short* Ws = wbuf + (st & 1) * (STAGE_C * 1280);

        // issue W[st+1] DMA into the buffer last read at stage st-1
        if (st >= 1 && st < N_STAGES - 1) {
            const char* src =
                (const char*)(Wb + (size_t)(c0 + (st + 1) * STAGE_C) * 1280);
            char* dst = (char*)(wbuf + ((st + 1) & 1) * (STAGE_C * 1280));
            #pragma unroll
            for (int it = 0; it < 2; ++it) {
                int f = tid + BLOCK * it;
                if (f < 480) GLD16(src + f * 16, dst + f * 16);
            }
            asm volatile("" ::: "memory");
        }

        if (!FIRST) {
            // ---- sweep1: 30 independent (c,n) chains over 4 waves ----
            #pragma unroll
            for (int k = 0; k < 8; ++k) {
                const int idx = wv + 4 * k;
                if (idx < 30) {
                    const int c = idx / 10;
                    const int n = idx - c * 10;
                    v8s wa = {0, 0, 0, 0, 0, 0, 0, 0};
                    if (quad == 0)
                        wa = *(const v8s*)(Ws + c * 1280 + n * 128 + b * 8);
                    const v8s xb =
                        *(const v8s*)(xs + (st * STAGE_C + c) * 128 + b * 8);
                    v4f u = __builtin_amdgcn_mfma_f32_16x16x32_bf16(
                        wa, xb, (v4f){0.f, 0.f, 0.f, 0.f}, 0, 0, 0);
                    const float4 v4 =
                        *(const float4*)(vst + b * 164 + n * 16 + quad * 4);
                    float l = u[0] * v4.x + u[1] * v4.y + u[2] * v4.z + u[3] * v4.w;
                    l += __shfl_xor(l, 16);
                    l += __shfl_xor(l, 32);
                    const float e1 = __expf(l);   // |l| <~ 3: no max-sub needed
                    if (quad == 0) cfl[c * 163 + n * 16 + b] = e1;
                }
            }
            // publish cfl; W[st+1] DMA stays in flight (no vmcnt drain)
            asm volatile("s_waitcnt lgkmcnt(0)" ::: "memory");
            __builtin_amdgcn_s_barrier();
        }

        // ---- sweep2: K=32 packs 3 c's (quad=c, quad3 zero-padded) ----
        {
            const bool valid = (quad < STAGE_C);
            const int  cl    = valid ? quad : 0;
            const v8s xq =
                *(const v8s*)(xs + (st * STAGE_C + cl) * 128 + b * 8);
            float xf[8];
            #pragma unroll
            for (int j = 0; j < 8; ++j) xf[j] = bf2f(xq[j]);

            if (FIRST) {
                union { v8s s; uint32_t u[4]; } zu;
                zu.u[0] = cvtpk(0.1f * xf[0], 0.1f * xf[1]);
                zu.u[1] = cvtpk(0.1f * xf[2], 0.1f * xf[3]);
                zu.u[2] = cvtpk(0.1f * xf[4], 0.1f * xf[5]);
                zu.u[3] = cvtpk(0.1f * xf[6], 0.1f * xf[7]);
                #pragma unroll
                for (int jj = 0; jj < 3; ++jj) {
                    if (jj < ncnt) {
                        const int n = wv + 4 * jj;
                        v8s wa = {0, 0, 0, 0, 0, 0, 0, 0};
                        if (valid)
                            wa = *(const v8s*)(Ws + cl * 1280 + n * 128 + b * 8);
                        sacc[jj] = __builtin_amdgcn_mfma_f32_16x16x32_bf16(
                            wa, zu.s, sacc[jj], 0, 0, 0);
                    }
                }
            } else {
                float Z = 0.f;
                #pragma unroll
                for (int n = 0; n < N_N; ++n) Z += cfl[cl * 163 + n * 16 + b];
                const float rzv = __builtin_amdgcn_rcpf(Z);
                #pragma unroll
                for (int jj = 0; jj < 3; ++jj) {
                    if (jj < ncnt) {
                        const int n = wv + 4 * jj;
                        const float cv = cfl[cl * 163 + n * 16 + b] * rzv;
                        union { v8s s; uint32_t u[4]; } zu;
                        zu.u[0] = cvtpk(cv * xf[0], cv * xf[1]);
                        zu.u[1] = cvtpk(cv * xf[2], cv * xf[3]);
                        zu.u[2] = cvtpk(cv * xf[4], cv * xf[5]);
                        zu.u[3] = cvtpk(cv * xf[6], cv * xf[7]);
                        v8s wa = {0, 0, 0, 0, 0, 0, 0, 0};
                        if (valid)
                            wa = *(const v8s*)(Ws + cl * 1280 + n * 128 + b * 8);
                        sacc[jj] = __builtin_amdgcn_mfma_f32_16x16x32_bf16(
                            wa, zu.s, sacc[jj], 0, 0, 0);
                    }
                }
            }
        }

        // end of stage: W[st+1] had a full stage of compute to land
        asm volatile("s_waitcnt vmcnt(0) lgkmcnt(0)" ::: "memory");
        __builtin_amdgcn_s_barrier();
    }

    // loop-end barrier already synced all Ws/xs/cfl readers -> comb alias safe
    #pragma unroll
    for (int jj = 0; jj < 3; ++jj) {
        if (jj < ncnt) {
            const int n = wv + 4 * jj;
            #pragma unroll
            for (int r = 0; r < 4; ++r)
                comb[b * 164 + n * 16 + quad * 4 + r] = sacc[jj][r];
        }
    }
    __syncthreads();
    // p_s is consumed cross-block after the grid barrier -> sc1 stores
    #pragma unroll
    for (int it = 0; it < 3; ++it) {
        int f = tid + BLOCK * it;
        if (f < 640) {
            int e = f * 4;
            int bb = e / 160, rem = e - bb * 160;
            v4f v = *(const v4f*)(comb + bb * 164 + rem);
            st16_sc1(&p_s[((size_t)chunk * B_N + gb0 + bb) * 160 + rem], v);
        }
    }
}

// ---- reduce+squash phase (in-kernel): wave wv handles g = wv*1024+bid ----
__device__ __forceinline__ void reduce_core(const float* __restrict__ p_s,
                                            float* __restrict__ vstG,
                                            float* __restrict__ out,
                                            int phase, int bid)
{
    const int wv   = threadIdx.x >> 6;
    const int lane = threadIdx.x & 63;
    const int g    = wv * 1024 + bid;        // covers 0..2559 with wv<3
    if (g >= B_N * N_N) return;              // wave-uniform, no barriers below
    const int q = lane & 3;
    const int h = lane >> 2;

    // p_s written cross-block -> sc1 loads (bypass possibly-stale L2)
    const float* base = p_s + (size_t)g * D_N + q * 4;
    v4f a0, a1, a2, a3;
    asm volatile(
        "global_load_dwordx4 %0, %4, off sc1\n\t"
        "global_load_dwordx4 %1, %5, off sc1\n\t"
        "global_load_dwordx4 %2, %6, off sc1\n\t"
        "global_load_dwordx4 %3, %7, off sc1\n\t"
        "s_waitcnt vmcnt(0)"
        : "=&v"(a0), "=&v"(a1), "=&v"(a2), "=&v"(a3)
        : "v"(base + (size_t)(h)      * 40960),
          "v"(base + (size_t)(h + 16) * 40960),
          "v"(base + (size_t)(h + 32) * 40960),
          "v"(base + (size_t)(h + 48) * 40960)
        : "memory");
    v4f s = a0 + a1 + a2 + a3;

    #pragma unroll
    for (int off = 4; off < 64; off <<= 1) {
        s[0] += __shfl_xor(s[0], off);
        s[1] += __shfl_xor(s[1], off);
        s[2] += __shfl_xor(s[2], off);
        s[3] += __shfl_xor(s[3], off);
    }
    float sq = s[0] * s[0] + s[1] * s[1] + s[2] * s[2] + s[3] * s[3];
    sq += __shfl_xor(sq, 1);
    sq += __shfl_xor(sq, 2);

    const float scale = (sq / (1.f + sq)) / (sqrtf(sq) + 1e-8f);
    const v4f v = {scale * s[0], scale * s[1], scale * s[2], scale * s[3]};

    if (h == 0) {
        if (phase == 2) {
            *(float4*)(&out[(size_t)g * D_N + q * 4]) =
                make_float4(v[0], v[1], v[2], v[3]);   // plain: kernel-end flush
        } else {
            const int bb = g / 10, n = g - bb * 10;
            float* vp = vstG + (size_t)(bb >> 4) * 2624 + (bb & 15) * 164 + n * 16 + q * 4;
            if (phase == 0) {
                st16_sc1(vp, v);
            } else {
                v4f o = ld16_sc1(vp);   // own phase-0 sc1 store, via LLC
                st16_sc1(vp, o + v);
            }
        }
    }
}

// ---- the whole routing pipeline in ONE dispatch (5 grid barriers) ----
__global__ __launch_bounds__(BLOCK, 4)
void fused_route(const short* __restrict__ Wb, const short* __restrict__ xt,
                 float* __restrict__ vstG, float* __restrict__ p_s,
                 float* __restrict__ out, uint32_t* bar)
{
    __shared__ __align__(16) char pool[POOL_BYTES];
    short* wbuf = (short*)pool;
    short* xs   = (short*)(pool + 15360);
    float* vst  = (float*)(pool + 19968);
    float* cfl  = (float*)(pool + 30464);
    float* comb = (float*)pool;

    const int chunk = blockIdx.x;
    const int btile = blockIdx.y;
    const int bid   = btile * 64 + chunk;   // 0..1023
    const int tid   = threadIdx.x;

    // ---- xs DMA once (xt immutable -> plain cached); persists all 3 passes ----
    {
        const char* src = (const char*)(xt + (size_t)(chunk * 16 + btile) * 2304);
        #pragma unroll
        for (int it = 0; it < 2; ++it) {
            int f = tid + BLOCK * it;
            if (f < 288) GLD16(src + f * 16, (char*)xs + f * 16);
        }
        asm volatile("" ::: "memory");
    }

    route_core<true>(wbuf, xs, vst, cfl, comb, Wb, vstG, p_s, chunk, btile);
    gbar(bar, bid, 1);
    reduce_core(p_s, vstG, out, 0, bid);
    gbar(bar, bid, 2);

    #pragma unroll 1
    for (int pass = 1; pass <= 2; ++pass) {
        route_core<false>(wbuf, xs, vst, cfl, comb, Wb, vstG, p_s, chunk, btile);
        gbar(bar, bid, (uint32_t)(2 * pass + 1));
        reduce_core(p_s, vstG, out, pass == 2 ? 2 : 1, bid);
        if (pass == 1) gbar(bar, bid, 4);
    }
}

extern "C" void kernel_launch(void* const* d_in, const int* in_sizes, int n_in,
                              void* d_out, int out_size, void* d_ws, size_t ws_size,
                              hipStream_t stream)
{
    const float* x = (const float*)d_in[0];
    const float* W = (const float*)d_in[1];
    float* out  = (float*)d_out;

    float* vstG = (float*)d_ws;
    float* p_s  = vstG + VSTG_FL;
    short* Wb   = (short*)(p_s + PS_FL);
    short* xt   = Wb + WB_SH;
    uint32_t* bar = (uint32_t*)(xt + XT_SH);

    conv_all<<<dim3(144 + 1024), BLOCK, 0, stream>>>(x, W, Wb, xt, bar);
    fused_route<<<dim3(C_CHUNKS, 16), BLOCK, 0, stream>>>(Wb, xt, vstG, p_s, out, bar);
}

// Round 4
// 122.453 us; speedup vs baseline: 2.0582x; 1.0842x over previous
//
#include <hip/hip_runtime.h>
#include <math.h>
#include <stdint.h>

// Problem dims (fixed by setup_inputs)
#define B_N 256
#define C_N 1152
#define I_N 8
#define N_N 10
#define D_N 16

constexpr int C_PER    = 18;             // c's per route block
constexpr int C_CHUNKS = C_N / C_PER;    // 64
constexpr int STAGE_C  = 3;              // c's per W staging round (double-buffered)
constexpr int N_STAGES = 6;
constexpr int BLOCK    = 256;
// route grid = 64 x 16 = 1024 blocks = exactly 4 blocks/CU -> full co-residency.
// Groups of 64 blocks (same btile = blockIdx.y) are data-independent: p_s for
// g=(b,n) comes only from the 64 chunk-blocks of b's btile, and vstG[btile]
// feeds only those blocks. All barriers are per-group (64 arrivals).

typedef short v8s __attribute__((ext_vector_type(8)));
typedef float v4f __attribute__((ext_vector_type(4)));

// ---- LDS pool (bytes), fused kernel ----
//   wbuf (short): 2 x [3c][10n][16d][8i] = 15360 @ 0      (DMA, linear, dbuf)
//   xs   (short): [18c][16b][8i]         =  4608 @ 15360  (reg-converted once)
//   vst  (float): [16b][164]             = 10496 @ 19968  (sc1 reg-staged)
//   cfl  (float): [3c][163]              =  1956 @ 30464
//   comb (float): [16b][164] ALIASES wbuf                 @ 0
constexpr int POOL_BYTES = 32432;   // 31.7 KB -> 4 blocks/CU

// ws layout (floats unless noted):
constexpr size_t VSTG_FL = 16 * 16 * 164;
constexpr size_t PS_FL   = (size_t)C_CHUNKS * B_N * 160;
constexpr size_t WB_SH   = (size_t)C_N * 1280;
constexpr int    BAR_W   = 16 * 64;  // 16 groups x 64 uints (256B stride)

#define GLD16(g, l)                                                         \
    __builtin_amdgcn_global_load_lds(                                       \
        (const uint32_t __attribute__((address_space(1)))*)(g),             \
        (uint32_t __attribute__((address_space(3)))*)(l), 16, 0, 0)

// ---- agent-coherent (LLC, bypass per-XCD L2) 16B load/store: sc1 flag ----
__device__ __forceinline__ void st16_sc1(float* p, v4f v) {
    asm volatile("global_store_dwordx4 %0, %1, off sc1"
                 :: "v"(p), "v"(v) : "memory");
}
__device__ __forceinline__ v4f ld16_sc1(const float* p) {
    v4f v;
    asm volatile("global_load_dwordx4 %0, %1, off sc1\n\t"
                 "s_waitcnt vmcnt(0)"
                 : "=&v"(v) : "v"(p) : "memory");
    return v;
}

// RNE pack of 2 f32 -> 1 u32 of 2 bf16 (bitwise identical to manual RNE)
__device__ __forceinline__ uint32_t cvtpk(float a, float b) {
    uint32_t r;
    asm("v_cvt_pk_bf16_f32 %0, %1, %2" : "=v"(r) : "v"(a), "v"(b));
    return r;
}
__device__ __forceinline__ float bf2f(short s) {
    return __uint_as_float(((uint32_t)(uint16_t)s) << 16);
}

// ---- K0: W fp32 -> bf16 [c][n][16d*8i] + barrier-state init ----
__global__ __launch_bounds__(BLOCK)
void conv_all(const float* __restrict__ W, short* __restrict__ Wb,
              uint32_t* __restrict__ bar)
{
    // barrier counters zeroed here, a dispatch BEFORE any use -> race-free
    // (harness re-poisons ws between iterations, so this must run every call)
    if (blockIdx.x == 0) {
        for (int i = threadIdx.x; i < BAR_W; i += BLOCK) bar[i] = 0u;
    }
    const int c0 = blockIdx.x * 8;
    const int cc = threadIdx.x >> 5;        // 8 c's per block
    const int k4 = threadIdx.x & 31;        // 32 float4 per (n,c)
    const float4* W4 = (const float4*)W;
    uint2* dst = (uint2*)Wb;
    for (int n = 0; n < N_N; ++n) {
        float4 v = W4[(size_t)n * 36864 + (size_t)(c0 + cc) * 32 + k4];
        dst[(((size_t)(c0 + cc) * 1280 + n * 128) >> 2) + k4] =
            make_uint2(cvtpk(v.x, v.y), cvtpk(v.z, v.w));
    }
}

// ---- per-group (64-block) fence-free barrier ----
// counter at bar[g*64], phase at bar[g*64+32] (separate cachelines).
// Arrive: one relaxed agent fetch_add. Last arriver resets the counter,
// drains (vmcnt retire => LLC-visible), bumps the monotonic phase. Spin on
// phase. No cache maintenance anywhere (all cross-block data is sc1).
__device__ __forceinline__ void gbar(uint32_t* bar, int group, uint32_t expect)
{
    asm volatile("s_waitcnt vmcnt(0) lgkmcnt(0)" ::: "memory");
    __syncthreads();
    if (threadIdx.x == 0) {
        uint32_t* cnt = &bar[group * 64];
        uint32_t* ph  = &bar[group * 64 + 32];
        uint32_t a = __hip_atomic_fetch_add(cnt, 1u, __ATOMIC_RELAXED,
                                            __HIP_MEMORY_SCOPE_AGENT);
        if (a == 63u) {
            __hip_atomic_store(cnt, 0u, __ATOMIC_RELAXED,
                               __HIP_MEMORY_SCOPE_AGENT);
            asm volatile("s_waitcnt vmcnt(0)" ::: "memory");
            __hip_atomic_fetch_add(ph, 1u, __ATOMIC_RELAXED,
                                   __HIP_MEMORY_SCOPE_AGENT);
        }
        while (__hip_atomic_load(ph, __ATOMIC_RELAXED,
                                 __HIP_MEMORY_SCOPE_AGENT) < expect)
            __builtin_amdgcn_s_sleep(2);
    }
    __syncthreads();
}

// ---- one routing pass ----
template <bool FIRST>
__device__ __forceinline__ void route_core(
    short* wbuf, const short* xs, float* vst, float* cfl, float* comb,
    const short* __restrict__ Wb, const float* __restrict__ vstG,
    float* __restrict__ p_s, int chunk, int btile)
{
    const int tid  = threadIdx.x;
    const int wv   = tid >> 6;
    const int lane = tid & 63;
    const int b    = lane & 15;   // D-col / B-col; also A-row m (=d)
    const int quad = lane >> 4;
    const int gb0  = btile * 16;
    const int c0   = chunk * C_PER;

    // ---- prologue: vst via sc1 reg-staging (cross-block data!), W0/W1 DMA ----
    if (!FIRST) {
        const float* src = vstG + (size_t)btile * 2624;
        const int f0 = tid;                       // < 656 always
        const int f1 = tid + 256;                 // < 656 always
        int f2 = tid + 512; f2 = (f2 < 656) ? f2 : 655;  // clamp: uniform count
        v4f t0, t1, t2;
        asm volatile(
            "global_load_dwordx4 %0, %3, off sc1\n\t"
            "global_load_dwordx4 %1, %4, off sc1\n\t"
            "global_load_dwordx4 %2, %5, off sc1\n\t"
            "s_waitcnt vmcnt(0)"
            : "=&v"(t0), "=&v"(t1), "=&v"(t2)
            : "v"(src + f0 * 4), "v"(src + f1 * 4), "v"(src + f2 * 4)
            : "memory");
        *(v4f*)((char*)vst + f0 * 16) = t0;
        *(v4f*)((char*)vst + f1 * 16) = t1;
        *(v4f*)((char*)vst + f2 * 16) = t2;   // f2 clamp: benign dup write
    }
    // W0 then W1 via cached global_load_lds (Wb immutable -> L2-warm reuse);
    // 480-split: every wave issues exactly 2 GLD16 per stage (uniform vmcnt)
    #pragma unroll
    for (int s0 = 0; s0 < 2; ++s0) {
        const char* src = (const char*)(Wb + (size_t)(c0 + s0 * STAGE_C) * 1280);
        char* dst = (char*)(wbuf + s0 * (STAGE_C * 1280));
        #pragma unroll
        for (int it = 0; it < 2; ++it) {
            int f = tid + BLOCK * it;
            if (f < 480) GLD16(src + f * 16, dst + f * 16);
        }
        asm volatile("" ::: "memory");
    }
    // vmcnt(2): W0 (and everything earlier) landed; W1 still in flight
    asm volatile("s_waitcnt vmcnt(2) lgkmcnt(0)" ::: "memory");
    __builtin_amdgcn_s_barrier();

    const int ncnt = (wv < 2) ? 3 : 2;   // wave wv owns n = wv, wv+4, (wv+8)
    v4f sacc[3];
    sacc[0] = (v4f){0.f, 0.f, 0.f, 0.f};
    sacc[1] = (v4f){0.f, 0.f, 0.f, 0.f};
    sacc[2] = (v4f){0.f, 0.f, 0.f, 0.f};

    for (int st = 0; st < N_STAGES; ++st) {
        const short* Ws = wbuf + (st & 1) * (STAGE_C * 1280);

        // issue W[st+1] DMA into the buffer last read at stage st-1
        if (st >= 1 && st < N_STAGES - 1) {
            const char* src =
                (const char*)(Wb + (size_t)(c0 + (st + 1) * STAGE_C) * 1280);
            char* dst = (char*)(wbuf + ((st + 1) & 1) * (STAGE_C * 1280));
            #pragma unroll
            for (int it = 0; it < 2; ++it) {
                int f = tid + BLOCK * it;
                if (f < 480) GLD16(src + f * 16, dst + f * 16);
            }
            asm volatile("" ::: "memory");
        }

        if (!FIRST) {
            // ---- sweep1: 30 independent (c,n) chains over 4 waves ----
            #pragma unroll
            for (int k = 0; k < 8; ++k) {
                const int idx = wv + 4 * k;
                if (idx < 30) {
                    const int c = idx / 10;
                    const int n = idx - c * 10;
                    v8s wa = {0, 0, 0, 0, 0, 0, 0, 0};
                    if (quad == 0)
                        wa = *(const v8s*)(Ws + c * 1280 + n * 128 + b * 8);
                    const v8s xb =
                        *(const v8s*)(xs + (st * STAGE_C + c) * 128 + b * 8);
                    v4f u = __builtin_amdgcn_mfma_f32_16x16x32_bf16(
                        wa, xb, (v4f){0.f, 0.f, 0.f, 0.f}, 0, 0, 0);
                    const float4 v4 =
                        *(const float4*)(vst + b * 164 + n * 16 + quad * 4);
                    float l = u[0] * v4.x + u[1] * v4.y + u[2] * v4.z + u[3] * v4.w;
                    l += __shfl_xor(l, 16);
                    l += __shfl_xor(l, 32);
                    const float e1 = __expf(l);   // |l| <~ 3: no max-sub needed
                    if (quad == 0) cfl[c * 163 + n * 16 + b] = e1;
                }
            }
            // publish cfl; W[st+1] DMA stays in flight (no vmcnt drain)
            asm volatile("s_waitcnt lgkmcnt(0)" ::: "memory");
            __builtin_amdgcn_s_barrier();
        }

        // ---- sweep2: K=32 packs 3 c's (quad=c, quad3 zero-padded) ----
        {
            const bool valid = (quad < STAGE_C);
            const int  cl    = valid ? quad : 0;
            const v8s xq =
                *(const v8s*)(xs + (st * STAGE_C + cl) * 128 + b * 8);
            float xf[8];
            #pragma unroll
            for (int j = 0; j < 8; ++j) xf[j] = bf2f(xq[j]);

            if (FIRST) {
                union { v8s s; uint32_t u[4]; } zu;
                zu.u[0] = cvtpk(0.1f * xf[0], 0.1f * xf[1]);
                zu.u[1] = cvtpk(0.1f * xf[2], 0.1f * xf[3]);
                zu.u[2] = cvtpk(0.1f * xf[4], 0.1f * xf[5]);
                zu.u[3] = cvtpk(0.1f * xf[6], 0.1f * xf[7]);
                #pragma unroll
                for (int jj = 0; jj < 3; ++jj) {
                    if (jj < ncnt) {
                        const int n = wv + 4 * jj;
                        v8s wa = {0, 0, 0, 0, 0, 0, 0, 0};
                        if (valid)
                            wa = *(const v8s*)(Ws + cl * 1280 + n * 128 + b * 8);
                        sacc[jj] = __builtin_amdgcn_mfma_f32_16x16x32_bf16(
                            wa, zu.s, sacc[jj], 0, 0, 0);
                    }
                }
            } else {
                float Z = 0.f;
                #pragma unroll
                for (int n = 0; n < N_N; ++n) Z += cfl[cl * 163 + n * 16 + b];
                const float rzv = __builtin_amdgcn_rcpf(Z);
                #pragma unroll
                for (int jj = 0; jj < 3; ++jj) {
                    if (jj < ncnt) {
                        const int n = wv + 4 * jj;
                        const float cv = cfl[cl * 163 + n * 16 + b] * rzv;
                        union { v8s s; uint32_t u[4]; } zu;
                        zu.u[0] = cvtpk(cv * xf[0], cv * xf[1]);
                        zu.u[1] = cvtpk(cv * xf[2], cv * xf[3]);
                        zu.u[2] = cvtpk(cv * xf[4], cv * xf[5]);
                        zu.u[3] = cvtpk(cv * xf[6], cv * xf[7]);
                        v8s wa = {0, 0, 0, 0, 0, 0, 0, 0};
                        if (valid)
                            wa = *(const v8s*)(Ws + cl * 1280 + n * 128 + b * 8);
                        sacc[jj] = __builtin_amdgcn_mfma_f32_16x16x32_bf16(
                            wa, zu.s, sacc[jj], 0, 0, 0);
                    }
                }
            }
        }

        // end of stage: W[st+1] had a full stage of compute to land
        asm volatile("s_waitcnt vmcnt(0) lgkmcnt(0)" ::: "memory");
        __builtin_amdgcn_s_barrier();
    }

    // loop-end barrier already synced all Ws/xs/cfl readers -> comb alias safe
    #pragma unroll
    for (int jj = 0; jj < 3; ++jj) {
        if (jj < ncnt) {
            const int n = wv + 4 * jj;
            #pragma unroll
            for (int r = 0; r < 4; ++r)
                comb[b * 164 + n * 16 + quad * 4 + r] = sacc[jj][r];
        }
    }
    __syncthreads();
    // p_s is consumed cross-block (within the group) -> sc1 stores
    #pragma unroll
    for (int it = 0; it < 3; ++it) {
        int f = tid + BLOCK * it;
        if (f < 640) {
            int e = f * 4;
            int bb = e / 160, rem = e - bb * 160;
            v4f v = *(const v4f*)(comb + bb * 164 + rem);
            st16_sc1(&p_s[((size_t)chunk * B_N + gb0 + bb) * 160 + rem], v);
        }
    }
}

// ---- reduce+squash, group-local: 160 g's over the group's 64 blocks ----
__device__ __forceinline__ void reduce_core(const float* __restrict__ p_s,
                                            float* __restrict__ vstG,
                                            float* __restrict__ out,
                                            int phase, int chunk, int btile)
{
    const int wv   = threadIdx.x >> 6;
    const int lane = threadIdx.x & 63;
    const int k    = wv * 64 + chunk;        // 0..191; valid < 160
    if (k >= 160) return;                    // wave-uniform (chunk is uniform)
    const int bb = k / 10, n = k - bb * 10;  // bb in [0,16), n in [0,10)
    const int g  = (btile * 16 + bb) * 10 + n;
    const int q = lane & 3;
    const int h = lane >> 2;

    // p_s written cross-block -> sc1 loads (bypass possibly-stale L2)
    const float* base = p_s + (size_t)g * D_N + q * 4;
    v4f a0, a1, a2, a3;
    asm volatile(
        "global_load_dwordx4 %0, %4, off sc1\n\t"
        "global_load_dwordx4 %1, %5, off sc1\n\t"
        "global_load_dwordx4 %2, %6, off sc1\n\t"
        "global_load_dwordx4 %3, %7, off sc1\n\t"
        "s_waitcnt vmcnt(0)"
        : "=&v"(a0), "=&v"(a1), "=&v"(a2), "=&v"(a3)
        : "v"(base + (size_t)(h)      * 40960),
          "v"(base + (size_t)(h + 16) * 40960),
          "v"(base + (size_t)(h + 32) * 40960),
          "v"(base + (size_t)(h + 48) * 40960)
        : "memory");
    v4f s = a0 + a1 + a2 + a3;

    #pragma unroll
    for (int off = 4; off < 64; off <<= 1) {
        s[0] += __shfl_xor(s[0], off);
        s[1] += __shfl_xor(s[1], off);
        s[2] += __shfl_xor(s[2], off);
        s[3] += __shfl_xor(s[3], off);
    }
    float sq = s[0] * s[0] + s[1] * s[1] + s[2] * s[2] + s[3] * s[3];
    sq += __shfl_xor(sq, 1);
    sq += __shfl_xor(sq, 2);

    const float scale = (sq / (1.f + sq)) / (sqrtf(sq) + 1e-8f);
    const v4f v = {scale * s[0], scale * s[1], scale * s[2], scale * s[3]};

    if (h == 0) {
        if (phase == 2) {
            *(float4*)(&out[(size_t)g * D_N + q * 4]) =
                make_float4(v[0], v[1], v[2], v[3]);   // plain: kernel-end flush
        } else {
            float* vp = vstG + (size_t)btile * 2624 + bb * 164 + n * 16 + q * 4;
            if (phase == 0) {
                st16_sc1(vp, v);
            } else {
                v4f o = ld16_sc1(vp);   // own phase-0 sc1 store, via LLC
                st16_sc1(vp, o + v);
            }
        }
    }
}

// ---- whole routing pipeline, ONE dispatch, per-group barriers only ----
__global__ __launch_bounds__(BLOCK, 4)
void fused_route(const float* __restrict__ x, const short* __restrict__ Wb,
                 float* __restrict__ vstG, float* __restrict__ p_s,
                 float* __restrict__ out, uint32_t* bar)
{
    __shared__ __align__(16) char pool[POOL_BYTES];
    short* wbuf = (short*)pool;
    short* xs   = (short*)(pool + 15360);
    float* vst  = (float*)(pool + 19968);
    float* cfl  = (float*)(pool + 30464);
    float* comb = (float*)pool;

    const int chunk = blockIdx.x;
    const int btile = blockIdx.y;     // == group id
    const int tid   = threadIdx.x;
    const int gb0   = btile * 16;
    const int c0    = chunk * C_PER;

    // ---- xs: convert x fp32 -> bf16 straight into LDS (no xt round-trip);
    //      persists across all 3 passes. 576 float4 over 256 threads. ----
    {
        const float4* x4 = (const float4*)x;
        #pragma unroll
        for (int it = 0; it < 3; ++it) {
            int f = tid + BLOCK * it;
            if (f < 576) {
                int b = f / 36, r = f - b * 36;  // r: 36 float4 per b (18c*8i)
                float4 v = x4[(size_t)(gb0 + b) * 2304 + c0 * 2 + r];
                int cp = r >> 1, i0 = (r & 1) * 4;
                *(uint2*)(xs + cp * 128 + b * 8 + i0) =
                    make_uint2(cvtpk(v.x, v.y), cvtpk(v.z, v.w));
            }
        }
        // drain the x loads so the prologue's vmcnt(2) counts only W DMA
        asm volatile("s_waitcnt vmcnt(0)" ::: "memory");
    }

    route_core<true>(wbuf, xs, vst, cfl, comb, Wb, vstG, p_s, chunk, btile);
    gbar(bar, btile, 1);
    reduce_core(p_s, vstG, out, 0, chunk, btile);
    gbar(bar, btile, 2);

    #pragma unroll 1
    for (int pass = 1; pass <= 2; ++pass) {
        route_core<false>(wbuf, xs, vst, cfl, comb, Wb, vstG, p_s, chunk, btile);
        gbar(bar, btile, (uint32_t)(2 * pass + 1));
        reduce_core(p_s, vstG, out, pass == 2 ? 2 : 1, chunk, btile);
        if (pass == 1) gbar(bar, btile, 4);
    }
}

extern "C" void kernel_launch(void* const* d_in, const int* in_sizes, int n_in,
                              void* d_out, int out_size, void* d_ws, size_t ws_size,
                              hipStream_t stream)
{
    const float* x = (const float*)d_in[0];
    const float* W = (const float*)d_in[1];
    float* out  = (float*)d_out;

    float* vstG = (float*)d_ws;
    float* p_s  = vstG + VSTG_FL;
    short* Wb   = (short*)(p_s + PS_FL);
    uint32_t* bar = (uint32_t*)(Wb + WB_SH);

    conv_all<<<dim3(144), BLOCK, 0, stream>>>(W, Wb, bar);
    fused_route<<<dim3(C_CHUNKS, 16), BLOCK, 0, stream>>>(x, Wb, vstG, p_s, out, bar);
}